// Round 1
// baseline (393.266 us; speedup 1.0000x reference)
//
#include <hip/hip_runtime.h>
#include <math.h>

#define Bb 2
#define Nn 512
#define RR 1024      // B*N rows
#define HH 8
#define DKk 16
#define PROJC 704    // 672 padded to multiple of 64
#define CONCATC 1280

#define SCALAR_SCALE 0.14433756729740643f  // 48^-0.5
#define POINT_SCALE  0.13608276348795434f  // 54^-0.5
#define PAIR_SCALE   0.5773502691896258f   // 3^-0.5

// ---------------------------------------------------------------- utilities
__device__ __forceinline__ float wred_sum(float v) {
#pragma unroll
  for (int o = 1; o < 64; o <<= 1) v += __shfl_xor(v, o);
  return v;
}
__device__ __forceinline__ float wred_max(float v) {
#pragma unroll
  for (int o = 1; o < 64; o <<= 1) v = fmaxf(v, __shfl_xor(v, o));
  return v;
}

// ------------------------------------------------- 1. gather padded Wcat (512 x 704)
__global__ __launch_bounds__(256) void gather_wcat(
    const float* __restrict__ Wqs, const float* __restrict__ Wks,
    const float* __restrict__ Wvs, const float* __restrict__ Wqp,
    const float* __restrict__ Wkp, const float* __restrict__ Wvp,
    float* __restrict__ Wcat) {
  int k = blockIdx.x;  // 0..511
  for (int c = threadIdx.x; c < PROJC; c += 256) {
    float v = 0.f;
    if (c < 128)      v = Wqs[k * 128 + c];
    else if (c < 256) v = Wks[k * 128 + c - 128];
    else if (c < 384) v = Wvs[k * 128 + c - 256];
    else if (c < 480) v = Wqp[k * 96 + c - 384];
    else if (c < 576) v = Wkp[k * 96 + c - 480];
    else if (c < 672) v = Wvp[k * 96 + c - 576];
    Wcat[k * PROJC + c] = v;
  }
}

// ------------------------------------------------- generic f32 tiled GEMM 32x32 tile
// C[M x N] = A[M x K] @ B[K x N] (+bias)(+relu). M,N mult of 32, K mult of 64.
__global__ __launch_bounds__(256) void gemm_f32(
    const float* __restrict__ A, int lda, const float* __restrict__ Bm, int ldb,
    float* __restrict__ C, int ldc, int K, const float* __restrict__ bias, int relu) {
  __shared__ float As[32][68];   // 68*4=272B rows: 16B aligned, banks (4r+k)%32
  __shared__ float Bs[64][32];
  const int t = threadIdx.x;
  const int bn = blockIdx.x * 32;
  const int bm = blockIdx.y * 32;
  float acc0 = 0.f, acc1 = 0.f, acc2 = 0.f, acc3 = 0.f;
  const int tr = t >> 3;          // 0..31
  const int tc = (t & 7) * 4;     // 0..28
  for (int k0 = 0; k0 < K; k0 += 64) {
#pragma unroll
    for (int ld = 0; ld < 2; ld++) {
      int idx = t + ld * 256;
      int ar = idx >> 4, ac = (idx & 15) * 4;
      float4 av = *reinterpret_cast<const float4*>(&A[(size_t)(bm + ar) * lda + k0 + ac]);
      *reinterpret_cast<float4*>(&As[ar][ac]) = av;
      int br = idx >> 3, bc = (idx & 7) * 4;
      float4 bv = *reinterpret_cast<const float4*>(&Bm[(size_t)(k0 + br) * ldb + bn + bc]);
      *reinterpret_cast<float4*>(&Bs[br][bc]) = bv;
    }
    __syncthreads();
#pragma unroll 8
    for (int k = 0; k < 64; k++) {
      float a = As[tr][k];
      float4 b4 = *reinterpret_cast<const float4*>(&Bs[k][tc]);
      acc0 += a * b4.x; acc1 += a * b4.y; acc2 += a * b4.z; acc3 += a * b4.w;
    }
    __syncthreads();
  }
  float4 o = make_float4(acc0, acc1, acc2, acc3);
  if (bias) {
    float4 bb = *reinterpret_cast<const float4*>(&bias[bn + tc]);
    o.x += bb.x; o.y += bb.y; o.z += bb.z; o.w += bb.w;
  }
  if (relu) {
    o.x = fmaxf(o.x, 0.f); o.y = fmaxf(o.y, 0.f);
    o.z = fmaxf(o.z, 0.f); o.w = fmaxf(o.w, 0.f);
  }
  *reinterpret_cast<float4*>(&C[(size_t)(bm + tr) * ldc + bn + tc]) = o;
}

// ------------------------------------------------- 3. rotate/translate points to global
__global__ __launch_bounds__(128) void pointxform(
    const float* __restrict__ proj, const float* __restrict__ rot,
    const float* __restrict__ trans, float* __restrict__ qp,
    float* __restrict__ kp, float* __restrict__ vp) {
  int bn = blockIdx.x;  // 0..1023
  int t = threadIdx.x;
  __shared__ float R[9];
  __shared__ float T[3];
  if (t < 9) R[t] = rot[bn * 9 + t];
  if (t < 3) T[t] = trans[bn * 3 + t];
  __syncthreads();
  if (t < 96) {
    int which = t >> 5;   // 0 q, 1 k, 2 v
    int pt = t & 31;      // h*4+p
    const float* src = proj + (size_t)bn * PROJC + 384 + which * 96 + pt * 3;
    float c0 = src[0], c1 = src[1], c2 = src[2];
    float* dst = (which == 0 ? qp : (which == 1 ? kp : vp)) + (size_t)bn * 96 + pt * 3;
#pragma unroll
    for (int r = 0; r < 3; r++)
      dst[r] = c0 * R[0 * 3 + r] + c1 * R[1 * 3 + r] + c2 * R[2 * 3 + r] + T[r];
  }
}

// ------------------------------------------------- 4. pairwise pass 1: pair logits
// pl[b][h][i][j] = (pair[b,i,j,:] . Wpair[:,h]) * PAIR_SCALE + b_pair[h]
__global__ __launch_bounds__(256) void pair_logits(
    const float* __restrict__ pair, const float* __restrict__ Wpair,
    const float* __restrict__ b_pair, float* __restrict__ pl) {
  int bi = blockIdx.x;  // b*512+i
  int b = bi >> 9, i = bi & 511;
  int t = threadIdx.x;
  __shared__ float Wpt[8][132];      // [h][d] padded
  __shared__ float chunk[32][132];   // 32 j rows x 128 d, padded
  __shared__ float row[8][516];      // output row per head, padded
  for (int idx = t; idx < 1024; idx += 256) {
    int d = idx >> 3, h = idx & 7;
    Wpt[h][d] = Wpair[idx];
  }
  __syncthreads();
  const int jl = t >> 3, h = t & 7;
  const float bph = b_pair[h];
  const float* psrc = pair + (size_t)bi * 512 * 128;
  for (int c = 0; c < 16; c++) {
    const float* src = psrc + (size_t)c * 32 * 128;
    for (int idx = t; idx < 1024; idx += 256) {
      float4 v = *reinterpret_cast<const float4*>(&src[idx * 4]);
      *reinterpret_cast<float4*>(&chunk[idx >> 5][(idx & 31) * 4]) = v;
    }
    __syncthreads();
    float s = 0.f;
#pragma unroll 8
    for (int d = 0; d < 128; d += 4) {
      float4 cv = *reinterpret_cast<const float4*>(&chunk[jl][d]);
      float4 wv = *reinterpret_cast<const float4*>(&Wpt[h][d]);
      s += cv.x * wv.x + cv.y * wv.y + cv.z * wv.z + cv.w * wv.w;
    }
    row[h][c * 32 + jl] = s * PAIR_SCALE + bph;
    __syncthreads();
  }
  for (int h2 = 0; h2 < 8; h2++) {
    float* dst = pl + (((size_t)(b * 8 + h2) * 512 + i) * 512);
    for (int j = t; j < 512; j += 256) dst[j] = row[h2][j];
  }
}

// ------------------------------------------------- 5. logits + softmax (in-place on pl)
__global__ __launch_bounds__(256) void logits_softmax(
    const float* __restrict__ proj, const float* __restrict__ qp,
    const float* __restrict__ kp, const float* __restrict__ pw,
    float* __restrict__ plattn) {
  int blk = blockIdx.x;  // (b*8+h)*512 + i
  int i = blk & 511;
  int bh = blk >> 9;
  int h = bh & 7, b = bh >> 3;
  int t = threadIdx.x;
  int bn_i = b * 512 + i;
  __shared__ float qrow[16];
  __shared__ float qprow[12];
  __shared__ float red[8];
  if (t < 16) qrow[t] = proj[(size_t)bn_i * PROJC + h * 16 + t];
  if (t < 12) qprow[t] = qp[(size_t)bn_i * 96 + h * 12 + t];
  __syncthreads();
  const float w = 0.5f * log1pf(__expf(pw[h])) * POINT_SCALE;
  float l[2];
#pragma unroll
  for (int r = 0; r < 2; r++) {
    int j = t + r * 256;
    int bn_j = b * 512 + j;
    const float* kr = proj + (size_t)bn_j * PROJC + 128 + h * 16;
    float s = 0.f;
#pragma unroll
    for (int d = 0; d < 16; d++) s += qrow[d] * kr[d];
    const float* kpr = kp + (size_t)bn_j * 96 + h * 12;
    float d2 = 0.f;
#pragma unroll
    for (int d = 0; d < 12; d++) {
      float df = qprow[d] - kpr[d];
      d2 += df * df;
    }
    l[r] = s * SCALAR_SCALE - w * d2 + plattn[(size_t)blk * 512 + j];
  }
  // block softmax over 512
  int wid = t >> 6, lane = t & 63;
  float m = wred_max(fmaxf(l[0], l[1]));
  if (lane == 0) red[wid] = m;
  __syncthreads();
  float M = fmaxf(fmaxf(red[0], red[1]), fmaxf(red[2], red[3]));
  float e0 = __expf(l[0] - M), e1 = __expf(l[1] - M);
  float s2 = wred_sum(e0 + e1);
  __syncthreads();
  if (lane == 0) red[wid] = s2;
  __syncthreads();
  float inv = 1.f / (red[0] + red[1] + red[2] + red[3]);
  plattn[(size_t)blk * 512 + t] = e0 * inv;
  plattn[(size_t)blk * 512 + t + 256] = e1 * inv;
}

// ------------------------------------------------- 6. pairwise pass 2 + attn outputs
__global__ __launch_bounds__(256) void attn_outputs(
    const float* __restrict__ attn, const float* __restrict__ pair,
    const float* __restrict__ proj, const float* __restrict__ vp,
    const float* __restrict__ rot, const float* __restrict__ trans,
    float* __restrict__ concat) {
  int bi = blockIdx.x;
  int b = bi >> 9, i = bi & 511;
  int t = threadIdx.x;
  __shared__ float at[8][516];
  __shared__ float chunk[32][132];
  __shared__ float pg[96];
  __shared__ float plcl[96];
  __shared__ float R[9];
  __shared__ float T[3];
  if (t < 9) R[t] = rot[bi * 9 + t];
  if (t < 3) T[t] = trans[bi * 3 + t];
  for (int h = 0; h < 8; h++) {
    const float* src = attn + (((size_t)(b * 8 + h) * 512 + i) * 512);
    for (int j = t; j < 512; j += 256) at[h][j] = src[j];
  }
  __syncthreads();
  // ---- out_pair: acc[h][d] = sum_j at[h][j]*pair[b,i,j,d]
  float pacc0 = 0.f, pacc1 = 0.f, pacc2 = 0.f, pacc3 = 0.f;
  const int d = t & 127, hg = (t >> 7) * 4;
  const float* psrc = pair + (size_t)bi * 512 * 128;
  for (int c = 0; c < 16; c++) {
    const float* src = psrc + (size_t)c * 32 * 128;
    for (int idx = t; idx < 1024; idx += 256) {
      float4 v = *reinterpret_cast<const float4*>(&src[idx * 4]);
      *reinterpret_cast<float4*>(&chunk[idx >> 5][(idx & 31) * 4]) = v;
    }
    __syncthreads();
#pragma unroll 4
    for (int jl = 0; jl < 32; jl++) {
      float pv = chunk[jl][d];
      int j = c * 32 + jl;
      pacc0 += at[hg + 0][j] * pv;
      pacc1 += at[hg + 1][j] * pv;
      pacc2 += at[hg + 2][j] * pv;
      pacc3 += at[hg + 3][j] * pv;
    }
    __syncthreads();
  }
  float* crow = concat + (size_t)bi * CONCATC;
  crow[256 + (hg + 0) * 128 + d] = pacc0;
  crow[256 + (hg + 1) * 128 + d] = pacc1;
  crow[256 + (hg + 2) * 128 + d] = pacc2;
  crow[256 + (hg + 3) * 128 + d] = pacc3;
  // ---- out_s (threads 0..127) and out_pg global (threads 128..223)
  if (t < 128) {
    int hs = t >> 4;
    float acc = 0.f;
    const float* base = proj + (size_t)b * 512 * PROJC + 256 + t;
#pragma unroll 4
    for (int j = 0; j < 512; j++) acc += at[hs][j] * base[(size_t)j * PROJC];
    crow[t] = acc;
  } else if (t < 224) {
    int ix = t - 128;           // h*12 + p*3 + r
    int hv = ix / 12;
    float acc = 0.f;
    const float* base = vp + (size_t)b * 512 * 96 + ix;
#pragma unroll 4
    for (int j = 0; j < 512; j++) acc += at[hv][j] * base[(size_t)j * 96];
    pg[ix] = acc;
  }
  __syncthreads();
  // ---- local frame: out_pl[c] = sum_r R[c][r]*(pg[r]-T[r])
  if (t < 96) {
    int hp = t / 3, cc = t % 3;
    float v = 0.f;
#pragma unroll
    for (int r = 0; r < 3; r++) v += R[cc * 3 + r] * (pg[hp * 3 + r] - T[r]);
    plcl[t] = v;
    crow[128 + t] = v;
  }
  __syncthreads();
  if (t < 32) {
    float v0 = plcl[t * 3], v1 = plcl[t * 3 + 1], v2 = plcl[t * 3 + 2];
    crow[224 + t] = sqrtf(v0 * v0 + v1 * v1 + v2 * v2 + 1e-8f);
  }
}

// ------------------------------------------------- layernorm (+residual)
__global__ __launch_bounds__(256) void ln_kernel(
    const float* __restrict__ in, const float* __restrict__ res,
    const float* __restrict__ g, const float* __restrict__ bt,
    float* __restrict__ out) {
  int row = blockIdx.x;
  int t = threadIdx.x;
  __shared__ float red[8];
  size_t base = (size_t)row * 512;
  float v0 = in[base + t] + res[base + t];
  float v1 = in[base + t + 256] + res[base + t + 256];
  int wid = t >> 6, lane = t & 63;
  float s = wred_sum(v0 + v1);
  if (lane == 0) red[wid] = s;
  __syncthreads();
  float mean = (red[0] + red[1] + red[2] + red[3]) * (1.f / 512.f);
  float d0 = v0 - mean, d1 = v1 - mean;
  float q = wred_sum(d0 * d0 + d1 * d1);
  __syncthreads();
  if (lane == 0) red[wid] = q;
  __syncthreads();
  float var = (red[0] + red[1] + red[2] + red[3]) * (1.f / 512.f);
  float rs = rsqrtf(var + 1e-3f);
  out[base + t] = d0 * rs * g[t] + bt[t];
  out[base + t + 256] = d1 * rs * g[t + 256] + bt[t + 256];
}

// ---------------------------------------------------------------- launcher
extern "C" void kernel_launch(void* const* d_in, const int* in_sizes, int n_in,
                              void* d_out, int out_size, void* d_ws, size_t ws_size,
                              hipStream_t stream) {
  const float* x      = (const float*)d_in[0];
  const float* pair   = (const float*)d_in[1];
  const float* rot    = (const float*)d_in[2];
  const float* trans  = (const float*)d_in[3];
  const float* Wqs    = (const float*)d_in[4];
  const float* Wks    = (const float*)d_in[5];
  const float* Wvs    = (const float*)d_in[6];
  const float* Wqp    = (const float*)d_in[7];
  const float* Wkp    = (const float*)d_in[8];
  const float* Wvp    = (const float*)d_in[9];
  const float* pw     = (const float*)d_in[10];
  const float* Wpair  = (const float*)d_in[11];
  const float* b_pair = (const float*)d_in[12];
  const float* Wo     = (const float*)d_in[13];
  const float* bo     = (const float*)d_in[14];
  const float* ln1g   = (const float*)d_in[15];
  const float* ln1b   = (const float*)d_in[16];
  const float* ln2g   = (const float*)d_in[17];
  const float* ln2b   = (const float*)d_in[18];
  const float* ffw1   = (const float*)d_in[19];
  const float* ffb1   = (const float*)d_in[20];
  const float* ffw2   = (const float*)d_in[21];
  const float* ffb2   = (const float*)d_in[22];
  const float* ffw3   = (const float*)d_in[23];
  const float* ffb3   = (const float*)d_in[24];
  float* out = (float*)d_out;

  float* ws = (float*)d_ws;
  float* Wcat = ws;           ws += 512 * PROJC;        // 360448
  float* proj = ws;           ws += (size_t)RR * PROJC; // 720896
  float* qp = ws;             ws += RR * 96;
  float* kp = ws;             ws += RR * 96;
  float* vp = ws;             ws += RR * 96;
  float* pl = ws;             ws += (size_t)Bb * HH * Nn * Nn;  // 16.8MB, reused as attn
  float* concat = ws;         ws += (size_t)RR * CONCATC;
  float* tmp1 = ws;           ws += RR * 512;
  float* a = ws;              ws += RR * 512;
  float* h1 = ws;             ws += RR * 512;
  float* h2 = ws;             ws += RR * 512;
  float* f = ws;              ws += RR * 512;

  dim3 b256(256);
  hipLaunchKernelGGL(gather_wcat, dim3(512), b256, 0, stream, Wqs, Wks, Wvs, Wqp, Wkp, Wvp, Wcat);
  // projections: x(1024x512) @ Wcat(512x704) -> proj
  hipLaunchKernelGGL(gemm_f32, dim3(PROJC / 32, RR / 32), b256, 0, stream,
                     x, 512, Wcat, PROJC, proj, PROJC, 512, (const float*)nullptr, 0);
  hipLaunchKernelGGL(pointxform, dim3(RR), dim3(128), 0, stream, proj, rot, trans, qp, kp, vp);
  hipLaunchKernelGGL(pair_logits, dim3(RR), b256, 0, stream, pair, Wpair, b_pair, pl);
  hipLaunchKernelGGL(logits_softmax, dim3(Bb * HH * Nn), b256, 0, stream, proj, qp, kp, pw, pl);
  hipLaunchKernelGGL(attn_outputs, dim3(RR), b256, 0, stream, pl, pair, proj, vp, rot, trans, concat);
  // concat(1024x1280) @ Wo(1280x512) + bo -> tmp1
  hipLaunchKernelGGL(gemm_f32, dim3(512 / 32, RR / 32), b256, 0, stream,
                     concat, CONCATC, Wo, 512, tmp1, 512, CONCATC, bo, 0);
  hipLaunchKernelGGL(ln_kernel, dim3(RR), b256, 0, stream, tmp1, x, ln1g, ln1b, a);
  hipLaunchKernelGGL(gemm_f32, dim3(512 / 32, RR / 32), b256, 0, stream,
                     a, 512, ffw1, 512, h1, 512, 512, ffb1, 1);
  hipLaunchKernelGGL(gemm_f32, dim3(512 / 32, RR / 32), b256, 0, stream,
                     h1, 512, ffw2, 512, h2, 512, 512, ffb2, 1);
  hipLaunchKernelGGL(gemm_f32, dim3(512 / 32, RR / 32), b256, 0, stream,
                     h2, 512, ffw3, 512, f, 512, 512, ffb3, 0);
  hipLaunchKernelGGL(ln_kernel, dim3(RR), b256, 0, stream, f, a, ln2g, ln2b, out);
}

// Round 2
// 293.790 us; speedup vs baseline: 1.3386x; 1.3386x over previous
//
#include <hip/hip_runtime.h>
#include <math.h>

#define Bb 2
#define Nn 512
#define RR 1024
#define HH 8
#define PROJC 704
#define CONCATC 1280

#define SCALAR_SCALE 0.14433756729740643f
#define POINT_SCALE  0.13608276348795434f
#define PAIR_SCALE   0.5773502691896258f

typedef __attribute__((ext_vector_type(4))) float f32x4;
typedef __attribute__((ext_vector_type(8))) short short8;
typedef __attribute__((ext_vector_type(8))) unsigned short ush8;

__device__ __forceinline__ float wred_sum(float v) {
#pragma unroll
  for (int o = 1; o < 64; o <<= 1) v += __shfl_xor(v, o);
  return v;
}
__device__ __forceinline__ float wred_max(float v) {
#pragma unroll
  for (int o = 1; o < 64; o <<= 1) v = fmaxf(v, __shfl_xor(v, o));
  return v;
}
__device__ __forceinline__ unsigned short f2bf(float f) {
  unsigned int u = __float_as_uint(f);
  unsigned int r = (u + 0x7FFFu + ((u >> 16) & 1u)) >> 16;
  return (unsigned short)r;
}

// ---------------- 1. gather + transpose + cvt Wcat_t bf16 [704][512]
__global__ __launch_bounds__(256) void gather_wcat_t(
    const float* __restrict__ Wqs, const float* __restrict__ Wks,
    const float* __restrict__ Wvs, const float* __restrict__ Wqp,
    const float* __restrict__ Wkp, const float* __restrict__ Wvp,
    unsigned short* __restrict__ Wt) {
  int c = blockIdx.x;  // 0..703
  for (int k = threadIdx.x; k < 512; k += 256) {
    float val = 0.f;
    if (c < 128)      val = Wqs[k * 128 + c];
    else if (c < 256) val = Wks[k * 128 + c - 128];
    else if (c < 384) val = Wvs[k * 128 + c - 256];
    else if (c < 480) val = Wqp[k * 96 + c - 384];
    else if (c < 576) val = Wkp[k * 96 + c - 480];
    else if (c < 672) val = Wvp[k * 96 + c - 576];
    Wt[(size_t)c * 512 + k] = f2bf(val);
  }
}

// ---------------- 2. transpose+cvt 4 weights: in f32 [K][512] -> out bf16 [512][K]
__global__ __launch_bounds__(256) void transp_cvt4(
    const float* __restrict__ w0, const float* __restrict__ w1,
    const float* __restrict__ w2, const float* __restrict__ w3,
    unsigned short* __restrict__ o0, unsigned short* __restrict__ o1,
    unsigned short* __restrict__ o2, unsigned short* __restrict__ o3) {
  int z = blockIdx.z;
  const float* in = (z == 0) ? w0 : (z == 1) ? w1 : (z == 2) ? w2 : w3;
  unsigned short* out = (z == 0) ? o0 : (z == 1) ? o1 : (z == 2) ? o2 : o3;
  int K = (z == 0) ? 1280 : 512;
  int k0 = blockIdx.y * 32, n0 = blockIdx.x * 32;
  if (k0 >= K) return;
  __shared__ float tile[32][33];
  int t = threadIdx.x;
  int r = t >> 3, cq = (t & 7) * 4;
  float4 v = *(const float4*)&in[(size_t)(k0 + r) * 512 + n0 + cq];
  tile[r][cq] = v.x; tile[r][cq + 1] = v.y; tile[r][cq + 2] = v.z; tile[r][cq + 3] = v.w;
  __syncthreads();
  ushort4 o4;
  o4.x = f2bf(tile[cq + 0][r]);
  o4.y = f2bf(tile[cq + 1][r]);
  o4.z = f2bf(tile[cq + 2][r]);
  o4.w = f2bf(tile[cq + 3][r]);
  *(ushort4*)&out[(size_t)(n0 + r) * K + k0 + cq] = o4;
}

// ---------------- 3. bf16 MFMA GEMM: C[M x N] = A[M x K](f32) @ Bt[N][K](bf16)
// tile 64x64, BK=64, 4 waves (2x2 quadrants of 32x32), frags 16x16x32.
__global__ __launch_bounds__(256) void gemm_bf16(
    const float* __restrict__ A, int lda,
    const unsigned short* __restrict__ Bt, int K,
    float* __restrict__ C, int ldc,
    const float* __restrict__ bias, int relu) {
  __shared__ unsigned short As[64][72];
  __shared__ unsigned short Bs[64][72];
  int t = threadIdx.x;
  int lane = t & 63, w = t >> 6;
  int wr = (w >> 1) * 32, wc = (w & 1) * 32;
  int fr = lane & 15, fk = (lane >> 4) * 8;
  f32x4 zero = {0.f, 0.f, 0.f, 0.f};
  f32x4 acc00 = zero, acc01 = zero, acc10 = zero, acc11 = zero;
  int sr = t >> 2, sc = (t & 3) * 16;
  int bm = blockIdx.y * 64, bn = blockIdx.x * 64;
  const float* Arow = A + (size_t)(bm + sr) * lda + sc;
  const unsigned short* Brow = Bt + (size_t)(bn + sr) * K + sc;
  for (int k0 = 0; k0 < K; k0 += 64) {
    float4 a0 = *(const float4*)(Arow + k0);
    float4 a1 = *(const float4*)(Arow + k0 + 4);
    float4 a2 = *(const float4*)(Arow + k0 + 8);
    float4 a3 = *(const float4*)(Arow + k0 + 12);
    ush8 b0 = *(const ush8*)(Brow + k0);
    ush8 b1 = *(const ush8*)(Brow + k0 + 8);
    ush8 ap0, ap1;
    ap0[0] = f2bf(a0.x); ap0[1] = f2bf(a0.y); ap0[2] = f2bf(a0.z); ap0[3] = f2bf(a0.w);
    ap0[4] = f2bf(a1.x); ap0[5] = f2bf(a1.y); ap0[6] = f2bf(a1.z); ap0[7] = f2bf(a1.w);
    ap1[0] = f2bf(a2.x); ap1[1] = f2bf(a2.y); ap1[2] = f2bf(a2.z); ap1[3] = f2bf(a2.w);
    ap1[4] = f2bf(a3.x); ap1[5] = f2bf(a3.y); ap1[6] = f2bf(a3.z); ap1[7] = f2bf(a3.w);
    *(ush8*)&As[sr][sc] = ap0;
    *(ush8*)&As[sr][sc + 8] = ap1;
    *(ush8*)&Bs[sr][sc] = b0;
    *(ush8*)&Bs[sr][sc + 8] = b1;
    __syncthreads();
#pragma unroll
    for (int kk = 0; kk < 64; kk += 32) {
      short8 af0 = *(const short8*)&As[wr + fr][kk + fk];
      short8 af1 = *(const short8*)&As[wr + 16 + fr][kk + fk];
      short8 bf0 = *(const short8*)&Bs[wc + fr][kk + fk];
      short8 bf1 = *(const short8*)&Bs[wc + 16 + fr][kk + fk];
      acc00 = __builtin_amdgcn_mfma_f32_16x16x32_bf16(af0, bf0, acc00, 0, 0, 0);
      acc01 = __builtin_amdgcn_mfma_f32_16x16x32_bf16(af0, bf1, acc01, 0, 0, 0);
      acc10 = __builtin_amdgcn_mfma_f32_16x16x32_bf16(af1, bf0, acc10, 0, 0, 0);
      acc11 = __builtin_amdgcn_mfma_f32_16x16x32_bf16(af1, bf1, acc11, 0, 0, 0);
    }
    __syncthreads();
  }
#pragma unroll
  for (int mi = 0; mi < 2; mi++) {
#pragma unroll
    for (int ni = 0; ni < 2; ni++) {
      f32x4 av = (mi == 0) ? ((ni == 0) ? acc00 : acc01) : ((ni == 0) ? acc10 : acc11);
      int col = bn + wc + ni * 16 + fr;
      float bv = bias ? bias[col] : 0.f;
#pragma unroll
      for (int r = 0; r < 4; r++) {
        int row = bm + wr + mi * 16 + (lane >> 4) * 4 + r;
        float v2 = av[r] + bv;
        if (relu) v2 = fmaxf(v2, 0.f);
        C[(size_t)row * ldc + col] = v2;
      }
    }
  }
}

// ---------------- 4. rotate/translate points to global
__global__ __launch_bounds__(128) void pointxform(
    const float* __restrict__ proj, const float* __restrict__ rot,
    const float* __restrict__ trans, float* __restrict__ qp,
    float* __restrict__ kp, float* __restrict__ vp) {
  int bn = blockIdx.x;
  int t = threadIdx.x;
  __shared__ float R[9];
  __shared__ float T[3];
  if (t < 9) R[t] = rot[bn * 9 + t];
  if (t < 3) T[t] = trans[bn * 3 + t];
  __syncthreads();
  if (t < 96) {
    int which = t >> 5;
    int pt = t & 31;
    const float* src = proj + (size_t)bn * PROJC + 384 + which * 96 + pt * 3;
    float c0 = src[0], c1 = src[1], c2 = src[2];
    float* dst = (which == 0 ? qp : (which == 1 ? kp : vp)) + (size_t)bn * 96 + pt * 3;
#pragma unroll
    for (int r = 0; r < 3; r++)
      dst[r] = c0 * R[0 * 3 + r] + c1 * R[1 * 3 + r] + c2 * R[2 * 3 + r] + T[r];
  }
}

// ---------------- 5. pair logits: W in registers, shfl reduce
__global__ __launch_bounds__(256) void pair_logits2(
    const float* __restrict__ pair, const float* __restrict__ Wpair,
    const float* __restrict__ b_pair, float* __restrict__ pl) {
  int bi = blockIdx.x;
  int b = bi >> 9, i = bi & 511;
  int t = threadIdx.x;
  int w = t >> 6, lane = t & 63;
  int rowlane = lane >> 4, dpart = lane & 15;
  __shared__ float rowbuf[512][12];
  float wv[8][8];
#pragma unroll
  for (int di = 0; di < 8; di++) {
    float4 u0 = *(const float4*)&Wpair[(dpart * 8 + di) * 8];
    float4 u1 = *(const float4*)&Wpair[(dpart * 8 + di) * 8 + 4];
    wv[di][0] = u0.x; wv[di][1] = u0.y; wv[di][2] = u0.z; wv[di][3] = u0.w;
    wv[di][4] = u1.x; wv[di][5] = u1.y; wv[di][6] = u1.z; wv[di][7] = u1.w;
  }
  float bp[8];
#pragma unroll
  for (int h = 0; h < 8; h++) bp[h] = b_pair[h];
  const float* pbase = pair + (size_t)bi * 512 * 128;
  for (int it = 0; it < 32; it++) {
    int j = it * 16 + w * 4 + rowlane;
    const float* pr = pbase + (size_t)j * 128 + dpart * 8;
    float4 p0 = *(const float4*)pr;
    float4 p1 = *(const float4*)(pr + 4);
    float p[8] = {p0.x, p0.y, p0.z, p0.w, p1.x, p1.y, p1.z, p1.w};
    float acc[8];
#pragma unroll
    for (int h = 0; h < 8; h++) acc[h] = 0.f;
#pragma unroll
    for (int di = 0; di < 8; di++)
#pragma unroll
      for (int h = 0; h < 8; h++) acc[h] += p[di] * wv[di][h];
#pragma unroll
    for (int h = 0; h < 8; h++) {
#pragma unroll
      for (int o = 1; o < 16; o <<= 1) acc[h] += __shfl_xor(acc[h], o);
    }
    if (dpart == 0) {
#pragma unroll
      for (int h = 0; h < 8; h++) rowbuf[j][h] = acc[h] * PAIR_SCALE + bp[h];
    }
  }
  __syncthreads();
#pragma unroll
  for (int h = 0; h < 8; h++) {
    float* dst = pl + (((size_t)(b * 8 + h) * 512 + i) * 512);
    dst[t] = rowbuf[t][h];
    dst[t + 256] = rowbuf[t + 256][h];
  }
}

// ---------------- 6. logits + softmax, block per (b,i), all 8 heads
__global__ __launch_bounds__(512) void logits_softmax2(
    const float* __restrict__ proj, const float* __restrict__ qp,
    const float* __restrict__ kp, const float* __restrict__ pw,
    float* __restrict__ pl) {
  int bi = blockIdx.x;
  int b = bi >> 9, i = bi & 511;
  int t = threadIdx.x;
  __shared__ float qs[128];
  __shared__ float qpi[96];
  __shared__ float wh[8];
  __shared__ float L[8][520];
  size_t bn_i = (size_t)b * 512 + i;
  if (t < 32) *(float4*)&qs[t * 4] = *(const float4*)&proj[bn_i * PROJC + t * 4];
  else if (t < 56) *(float4*)&qpi[(t - 32) * 4] = *(const float4*)&qp[bn_i * 96 + (t - 32) * 4];
  else if (t < 64) wh[t - 56] = 0.5f * log1pf(__expf(pw[t - 56])) * POINT_SCALE;
  __syncthreads();
  int j = t;
  const float* kr = proj + ((size_t)b * 512 + j) * PROJC + 128;
  const float* kpr = kp + ((size_t)b * 512 + j) * 96;
#pragma unroll
  for (int h = 0; h < 8; h++) {
    float s = 0.f;
#pragma unroll
    for (int d = 0; d < 16; d++) s += qs[h * 16 + d] * kr[h * 16 + d];
    float d2 = 0.f;
#pragma unroll
    for (int p = 0; p < 12; p++) {
      float df = qpi[h * 12 + p] - kpr[h * 12 + p];
      d2 += df * df;
    }
    L[h][j] = s * SCALAR_SCALE - wh[h] * d2 +
              pl[(((size_t)(b * 8 + h) * 512) + i) * 512 + j];
  }
  __syncthreads();
  int w = t >> 6, lane = t & 63;
  float v[8];
#pragma unroll
  for (int q = 0; q < 8; q++) v[q] = L[w][lane + q * 64];
  float m = fmaxf(fmaxf(fmaxf(v[0], v[1]), fmaxf(v[2], v[3])),
                  fmaxf(fmaxf(v[4], v[5]), fmaxf(v[6], v[7])));
  m = wred_max(m);
  float s = 0.f;
#pragma unroll
  for (int q = 0; q < 8; q++) { v[q] = __expf(v[q] - m); s += v[q]; }
  s = wred_sum(s);
  float inv = 1.f / s;
  float* dst = pl + (((size_t)(b * 8 + w) * 512) + i) * 512;
#pragma unroll
  for (int q = 0; q < 8; q++) dst[lane + q * 64] = v[q] * inv;
}

// ---------------- 7. attn outputs: pair pass 2 + out_s + points
__global__ __launch_bounds__(256) void attn_outputs2(
    const float* __restrict__ attn, const float* __restrict__ pair,
    const float* __restrict__ proj, const float* __restrict__ vp,
    const float* __restrict__ rot, const float* __restrict__ trans,
    float* __restrict__ concat) {
  int bi = blockIdx.x;
  int b = bi >> 9, i = bi & 511;
  int t = threadIdx.x;
  __shared__ float at[8][520];
  __shared__ float red[128][8];
  __shared__ float pg[96];
  __shared__ float plcl[96];
  __shared__ float R[9];
  __shared__ float T[3];
  if (t < 9) R[t] = rot[bi * 9 + t];
  if (t < 3) T[t] = trans[bi * 3 + t];
  {
    int h = t >> 5, j0 = (t & 31) * 16;
    const float* src = attn + (((size_t)(b * 8 + h) * 512 + i) * 512) + j0;
#pragma unroll
    for (int q = 0; q < 4; q++)
      *(float4*)&at[h][j0 + q * 4] = *(const float4*)&src[q * 4];
  }
  __syncthreads();
  int d = t & 127, half = t >> 7;
  float acc[8];
#pragma unroll
  for (int h = 0; h < 8; h++) acc[h] = 0.f;
  {
    const float* pp = pair + ((size_t)bi * 512 + half * 256) * 128 + d;
    int jb = half * 256;
    for (int jg = 0; jg < 64; jg++) {
      int j = jg * 4;
      float p0 = pp[(size_t)(j + 0) * 128];
      float p1 = pp[(size_t)(j + 1) * 128];
      float p2 = pp[(size_t)(j + 2) * 128];
      float p3 = pp[(size_t)(j + 3) * 128];
#pragma unroll
      for (int h = 0; h < 8; h++) {
        float4 a = *(const float4*)&at[h][jb + j];
        acc[h] += a.x * p0 + a.y * p1 + a.z * p2 + a.w * p3;
      }
    }
  }
  if (half) {
#pragma unroll
    for (int h = 0; h < 8; h++) red[d][h] = acc[h];
  }
  __syncthreads();
  float* crow = concat + (size_t)bi * CONCATC;
  if (!half) {
#pragma unroll
    for (int h = 0; h < 8; h++) crow[256 + h * 128 + d] = acc[h] + red[d][h];
  }
  if (t < 128) {
    int hs = t >> 4;
    float a2 = 0.f;
    const float* base = proj + (size_t)b * 512 * PROJC + 256 + t;
    for (int j = 0; j < 512; j += 4) {
      float4 av = *(const float4*)&at[hs][j];
      a2 += av.x * base[(size_t)j * PROJC] + av.y * base[(size_t)(j + 1) * PROJC] +
            av.z * base[(size_t)(j + 2) * PROJC] + av.w * base[(size_t)(j + 3) * PROJC];
    }
    crow[t] = a2;
  } else if (t < 224) {
    int ix = t - 128;
    int hv = ix / 12;
    float a2 = 0.f;
    const float* base = vp + (size_t)b * 512 * 96 + ix;
    for (int j = 0; j < 512; j += 4) {
      float4 av = *(const float4*)&at[hv][j];
      a2 += av.x * base[(size_t)j * 96] + av.y * base[(size_t)(j + 1) * 96] +
            av.z * base[(size_t)(j + 2) * 96] + av.w * base[(size_t)(j + 3) * 96];
    }
    pg[ix] = a2;
  }
  __syncthreads();
  if (t < 96) {
    int hp = t / 3, cc = t % 3;
    float v2 = 0.f;
#pragma unroll
    for (int r = 0; r < 3; r++) v2 += R[cc * 3 + r] * (pg[hp * 3 + r] - T[r]);
    plcl[t] = v2;
    crow[128 + t] = v2;
  }
  __syncthreads();
  if (t < 32) {
    float v0 = plcl[t * 3], v1 = plcl[t * 3 + 1], v2 = plcl[t * 3 + 2];
    crow[224 + t] = sqrtf(v0 * v0 + v1 * v1 + v2 * v2 + 1e-8f);
  }
}

// ---------------- 8. layernorm (+residual)
__global__ __launch_bounds__(256) void ln_kernel(
    const float* __restrict__ in, const float* __restrict__ res,
    const float* __restrict__ g, const float* __restrict__ bt,
    float* __restrict__ out) {
  int row = blockIdx.x;
  int t = threadIdx.x;
  __shared__ float red[8];
  size_t base = (size_t)row * 512;
  float v0 = in[base + t] + res[base + t];
  float v1 = in[base + t + 256] + res[base + t + 256];
  int wid = t >> 6, lane = t & 63;
  float s = wred_sum(v0 + v1);
  if (lane == 0) red[wid] = s;
  __syncthreads();
  float mean = (red[0] + red[1] + red[2] + red[3]) * (1.f / 512.f);
  float d0 = v0 - mean, d1 = v1 - mean;
  float q = wred_sum(d0 * d0 + d1 * d1);
  __syncthreads();
  if (lane == 0) red[wid] = q;
  __syncthreads();
  float var = (red[0] + red[1] + red[2] + red[3]) * (1.f / 512.f);
  float rs = rsqrtf(var + 1e-3f);
  out[base + t] = d0 * rs * g[t] + bt[t];
  out[base + t + 256] = d1 * rs * g[t + 256] + bt[t + 256];
}

// ---------------------------------------------------------------- launcher
extern "C" void kernel_launch(void* const* d_in, const int* in_sizes, int n_in,
                              void* d_out, int out_size, void* d_ws, size_t ws_size,
                              hipStream_t stream) {
  const float* x      = (const float*)d_in[0];
  const float* pair   = (const float*)d_in[1];
  const float* rot    = (const float*)d_in[2];
  const float* trans  = (const float*)d_in[3];
  const float* Wqs    = (const float*)d_in[4];
  const float* Wks    = (const float*)d_in[5];
  const float* Wvs    = (const float*)d_in[6];
  const float* Wqp    = (const float*)d_in[7];
  const float* Wkp    = (const float*)d_in[8];
  const float* Wvp    = (const float*)d_in[9];
  const float* pw     = (const float*)d_in[10];
  const float* Wpair  = (const float*)d_in[11];
  const float* b_pair = (const float*)d_in[12];
  const float* Wo     = (const float*)d_in[13];
  const float* bo     = (const float*)d_in[14];
  const float* ln1g   = (const float*)d_in[15];
  const float* ln1b   = (const float*)d_in[16];
  const float* ln2g   = (const float*)d_in[17];
  const float* ln2b   = (const float*)d_in[18];
  const float* ffw1   = (const float*)d_in[19];
  const float* ffb1   = (const float*)d_in[20];
  const float* ffw2   = (const float*)d_in[21];
  const float* ffb2   = (const float*)d_in[22];
  const float* ffw3   = (const float*)d_in[23];
  const float* ffb3   = (const float*)d_in[24];
  float* out = (float*)d_out;

  float* ws = (float*)d_ws;
  unsigned short* Wcat_t = (unsigned short*)ws; ws += (704 * 512) / 2;
  unsigned short* Wo_t   = (unsigned short*)ws; ws += (512 * 1280) / 2;
  unsigned short* ff1_t  = (unsigned short*)ws; ws += (512 * 512) / 2;
  unsigned short* ff2_t  = (unsigned short*)ws; ws += (512 * 512) / 2;
  unsigned short* ff3_t  = (unsigned short*)ws; ws += (512 * 512) / 2;
  float* proj   = ws; ws += (size_t)RR * PROJC;
  float* qp     = ws; ws += RR * 96;
  float* kp     = ws; ws += RR * 96;
  float* vp     = ws; ws += RR * 96;
  float* pl     = ws; ws += (size_t)Bb * HH * Nn * Nn;
  float* concat = ws; ws += (size_t)RR * CONCATC;
  float* tmp1   = ws; ws += RR * 512;
  float* a      = ws; ws += RR * 512;
  float* h1     = ws; ws += RR * 512;
  float* h2     = ws; ws += RR * 512;
  float* f      = ws; ws += RR * 512;

  dim3 b256(256);
  hipLaunchKernelGGL(gather_wcat_t, dim3(704), b256, 0, stream,
                     Wqs, Wks, Wvs, Wqp, Wkp, Wvp, Wcat_t);
  hipLaunchKernelGGL(transp_cvt4, dim3(16, 40, 4), b256, 0, stream,
                     Wo, ffw1, ffw2, ffw3, Wo_t, ff1_t, ff2_t, ff3_t);
  hipLaunchKernelGGL(gemm_bf16, dim3(11, 16), b256, 0, stream,
                     x, 512, Wcat_t, 512, proj, PROJC, (const float*)nullptr, 0);
  hipLaunchKernelGGL(pointxform, dim3(RR), dim3(128), 0, stream,
                     proj, rot, trans, qp, kp, vp);
  hipLaunchKernelGGL(pair_logits2, dim3(RR), b256, 0, stream,
                     pair, Wpair, b_pair, pl);
  hipLaunchKernelGGL(logits_softmax2, dim3(RR), dim3(512), 0, stream,
                     proj, qp, kp, pw, pl);
  hipLaunchKernelGGL(attn_outputs2, dim3(RR), b256, 0, stream,
                     pl, pair, proj, vp, rot, trans, concat);
  hipLaunchKernelGGL(gemm_bf16, dim3(8, 16), b256, 0, stream,
                     concat, CONCATC, Wo_t, 1280, tmp1, 512, bo, 0);
  hipLaunchKernelGGL(ln_kernel, dim3(RR), b256, 0, stream, tmp1, x, ln1g, ln1b, a);
  hipLaunchKernelGGL(gemm_bf16, dim3(8, 16), b256, 0, stream,
                     a, 512, ff1_t, 512, h1, 512, ffb1, 1);
  hipLaunchKernelGGL(gemm_bf16, dim3(8, 16), b256, 0, stream,
                     h1, 512, ff2_t, 512, h2, 512, ffb2, 1);
  hipLaunchKernelGGL(gemm_bf16, dim3(8, 16), b256, 0, stream,
                     h2, 512, ff3_t, 512, f, 512, ffb3, 0);
  hipLaunchKernelGGL(ln_kernel, dim3(RR), b256, 0, stream, f, a, ln2g, ln2b, out);
}